// Round 1
// baseline (2403.734 us; speedup 1.0000x reference)
//
#include <hip/hip_runtime.h>
#include <float.h>
#include <math.h>

#define NQ 2048
#define NT 100000
#define DIM 512
#define KTOP 5
#define QTILE 128
#define TTILE 128
#define NTPC 13             // t-tiles per chunk
#define CHUNK (NTPC*TTILE)  // 1664
#define NCH 64              // chunk id space; 8 chunks per XCD
#define TBLKS 782           // ceil(NT/128) -> valid 128-row t-tile blocks
#define TPAD (TBLKS*128)    // 100096
#define QBLKS 16            // NQ/128
#define NSUB 8              // t-sub-blocks per chunk (tiles {2,2,1,2,2,1,2,1})
#define CV_TBLKS (TBLKS*16) // 12512 convert tasks for T
#define CV_XBLKS ((NQ/128)*16) // 256 convert tasks for x

typedef float f32x4 __attribute__((ext_vector_type(4)));
typedef short s16x8 __attribute__((ext_vector_type(8)));
typedef unsigned int u32;

__device__ __forceinline__ int tsub_start(int ts) { return (13 * ts + 7) >> 3; }

__device__ __forceinline__ bool lt_pair(float v1, int i1, float v2, int i2) {
  return v1 < v2 || (v1 == v2 && i1 < i2);
}

__device__ __forceinline__ void ins5(float* tv, int* tix, float sc, int idx) {
  if (lt_pair(sc, idx, tv[4], tix[4])) {
    tv[4] = sc; tix[4] = idx;
#pragma unroll
    for (int p = 4; p > 0; --p)
      if (lt_pair(tv[p], tix[p], tv[p - 1], tix[p - 1])) {
        float tf = tv[p]; tv[p] = tv[p - 1]; tv[p - 1] = tf;
        int tn = tix[p]; tix[p] = tix[p - 1]; tix[p - 1] = tn;
      }
  }
}

__device__ __forceinline__ void merge5(float* av, int* ai, const float* bv, const int* bi) {
  float nv[5]; int ni[5];
#pragma unroll
  for (int s = 0; s < 5; ++s) {
    if (lt_pair(av[s], ai[s], bv[4 - s], bi[4 - s])) { nv[s] = av[s]; ni[s] = ai[s]; }
    else { nv[s] = bv[4 - s]; ni[s] = bi[4 - s]; }
  }
#pragma unroll
  for (int a = 0; a < 5; ++a)
#pragma unroll
    for (int b = 0; b < 4 - a; ++b)
      if (lt_pair(nv[b + 1], ni[b + 1], nv[b], ni[b])) {
        float tf = nv[b]; nv[b] = nv[b + 1]; nv[b + 1] = tf;
        int tn = ni[b]; ni[b] = ni[b + 1]; ni[b + 1] = tn;
      }
#pragma unroll
  for (int s = 0; s < 5; ++s) { av[s] = nv[s]; ai[s] = ni[s]; }
}

// ---------------- convert: fp32 -> frag-major (hi,mid) bf16, LDS-transposed ----
// One block per (src, blk128, kbi): reads 128 rows x 32 cols fp32 (coalesced
// 128B row segments), converts, transposes to frag order in LDS, writes one
// contiguous 8KB slice per array (fully coalesced: 4096 shorts = 256 thr x 16).
// Norms via atomicAdd of per-(row,kbi) partials (t2/x2 zeroed by memsetAsync).
__global__ __launch_bounds__(256) void convert_kernel(
    const float* __restrict__ x, const float* __restrict__ T,
    short* __restrict__ xhi, short* __restrict__ xmid,
    short* __restrict__ thi, short* __restrict__ tmid,
    float* __restrict__ t2, float* __restrict__ x2) {
  __shared__ short lh[4096];
  __shared__ short lm[4096];
  const int bid = blockIdx.x;
  const bool isT = bid < CV_TBLKS;
  const int task = isT ? bid : bid - CV_TBLKS;
  const int blk = task >> 4, kbi = task & 15;
  const float* src = isT ? T : x;
  short* dhi = isT ? thi : xhi;
  short* dmid = isT ? tmid : xmid;
  float* nrm = isT ? t2 : x2;
  const int nsrc = isT ? NT : NQ;

  const int t = threadIdx.x;
  const int rr = t >> 1, half = t & 1;
  const int grow = blk * 128 + rr;
  const int rs = grow < nsrc ? grow : nsrc - 1;
  const float* p = src + (size_t)rs * DIM + kbi * 32 + half * 16;
  f32x4 v[4];
#pragma unroll
  for (int i = 0; i < 4; ++i) v[i] = ((const f32x4*)p)[i];

  float ss = 0.f;
#pragma unroll
  for (int g = 0; g < 2; ++g) {
    s16x8 hv, mv;
#pragma unroll
    for (int e = 0; e < 8; ++e) {
      int i = g * 8 + e;
      float f = v[i >> 2][i & 3];
      ss = fmaf(f, f, ss);
      u32 u = __builtin_bit_cast(u32, f);
      u32 r1 = u + 0x7FFFu + ((u >> 16) & 1u);        // RNE to bf16
      float resid = f - __builtin_bit_cast(float, r1 & 0xFFFF0000u);
      u32 u2 = __builtin_bit_cast(u32, resid);
      u32 r2 = u2 + 0x7FFFu + ((u2 >> 16) & 1u);
      hv[e] = (short)(r1 >> 16);
      mv[e] = (short)(r2 >> 16);
    }
    // frag unit: tile = rr>>4, quad = half*2+g, m = rr&15
    int unit = (rr >> 4) * 64 + (half * 2 + g) * 16 + (rr & 15);
    *(s16x8*)(lh + unit * 8) = hv;
    *(s16x8*)(lm + unit * 8) = mv;
  }
  ss += __shfl_xor(ss, 1, 64);       // pair (t, t^1) share a row
  if (half == 0 && grow < nsrc) atomicAdd(nrm + grow, ss);

  __syncthreads();
  // slice = 4096 shorts per array; thread t copies shorts [t*16, t*16+16)
  size_t obase = ((size_t)(blk * 16 + kbi)) * 4096 + t * 16;
  *(s16x8*)(dhi + obase)      = *(const s16x8*)(lh + t * 16);
  *(s16x8*)(dhi + obase + 8)  = *(const s16x8*)(lh + t * 16 + 8);
  *(s16x8*)(dmid + obase)     = *(const s16x8*)(lm + t * 16);
  *(s16x8*)(dmid + obase + 8) = *(const s16x8*)(lm + t * 16 + 8);
}

// pointer-bump fragment load: 4 x 16B per array at i*1024B immediates,
// then advance all pointers by one kbi slab (512 s16x8 units = 8192 B).
__device__ __forceinline__ void load_frags(
    const s16x8*& pah, const s16x8*& pam, const s16x8*& pbh, const s16x8*& pbm,
    s16x8* ah, s16x8* am, s16x8* bh, s16x8* bm) {
#pragma unroll
  for (int i = 0; i < 4; ++i) {
    ah[i] = pah[i * 64];
    am[i] = pam[i * 64];
    bh[i] = pbh[i * 64];
    bm[i] = pbm[i * 64];
  }
  pah += 512; pam += 512; pbh += 512; pbm += 512;
}

__device__ __forceinline__ void do_mfma(const s16x8* ah, const s16x8* am,
                                        const s16x8* bh, const s16x8* bm,
                                        f32x4 acc[4][4]) {
#pragma unroll
  for (int j = 0; j < 4; ++j)
#pragma unroll
    for (int i = 0; i < 4; ++i) {
      acc[i][j] = __builtin_amdgcn_mfma_f32_16x16x32_bf16(ah[i], bh[j], acc[i][j], 0, 0, 0);
      acc[i][j] = __builtin_amdgcn_mfma_f32_16x16x32_bf16(ah[i], bm[j], acc[i][j], 0, 0, 0);
      acc[i][j] = __builtin_amdgcn_mfma_f32_16x16x32_bf16(am[i], bh[j], acc[i][j], 0, 0, 0);
    }
}

// ---------------- main: barrier-free K-loop, direct global->VGPR fragments ----
// Grid 8192: bid = xcd + 8*(inner + 128*chunkHigh); inner = tsub*16 + qblk.
// Per XCD the ~96 co-resident blocks (3/CU x 32 CU) = 16 qblk x 6 tsub of ONE
// chunk -> B working set <= 10 tiles x 256KB = 2.6 MB, fits the 4 MB XCD L2.
// launch_bounds(256,3): target 3 waves/SIMD (12 waves/CU) for latency hiding.
__global__ __launch_bounds__(256, 3) void knn_mfma(
    const short* __restrict__ xhi, const short* __restrict__ xmid,
    const short* __restrict__ thi, const short* __restrict__ tmid,
    const float* __restrict__ t2g,
    float* __restrict__ pvals, unsigned char* __restrict__ pidx8) {
  __shared__ float scr_all[4 * 1280];  // per-wave epilogue scratch (20 KB)

  const int tid = threadIdx.x;
  const int w = tid >> 6;
  const int l = tid & 63;
  const int bid = blockIdx.x;
  const int rest = bid >> 3;
  const int inner = rest & 127;
  const int chunk = (bid & 7) + 8 * (rest >> 7);
  const int qblk = inner & 15;
  const int tsub = inner >> 4;                 // 0..7
  const int tstart = tsub_start(tsub);
  const int tend = tsub_start(tsub + 1);
  const int q0 = qblk * QTILE;
  const int wr = (w >> 1) * 64;
  const int wc = (w & 1) * 64;
  const int arow = wr >> 4;
  const int bcol = wc >> 4;

  float tv[KTOP]; int tix[KTOP];
#pragma unroll
  for (int s = 0; s < KTOP; ++s) { tv[s] = FLT_MAX; tix[s] = 0x7FFFFFFF; }

#pragma unroll 1
  for (int tt = tstart; tt < tend; ++tt) {
    const int bblk = chunk * NTPC + tt;
    if (bblk >= TBLKS) continue;   // fully past NT: partials stay FLT_MAX
    const int jbase = bblk * TTILE;
    f32x4 acc[4][4];
#pragma unroll
    for (int i = 0; i < 4; ++i)
#pragma unroll
      for (int j = 0; j < 4; ++j) acc[i][j] = (f32x4){0.f, 0.f, 0.f, 0.f};

    s16x8 ah0[4], am0[4], bh0[4], bm0[4];
    s16x8 ah1[4], am1[4], bh1[4], bm1[4];
    // frag pointers in s16x8 units; kbi stride = 512 units (8192 B)
    const size_t ao = (size_t)(qblk * 16) * 512 + (size_t)(arow * 64 + l);
    const size_t bo = (size_t)(bblk * 16) * 512 + (size_t)(bcol * 64 + l);
    const s16x8* pah = (const s16x8*)xhi + ao;
    const s16x8* pam = (const s16x8*)xmid + ao;
    const s16x8* pbh = (const s16x8*)thi + bo;
    const s16x8* pbm = (const s16x8*)tmid + bo;

    load_frags(pah, pam, pbh, pbm, ah0, am0, bh0, bm0);
#pragma unroll 1
    for (int step = 0; step < 8; ++step) {
      load_frags(pah, pam, pbh, pbm, ah1, am1, bh1, bm1);
      do_mfma(ah0, am0, bh0, bm0, acc);
      if (step < 7)
        load_frags(pah, pam, pbh, pbm, ah0, am0, bh0, bm0);
      do_mfma(ah1, am1, bh1, bm1, acc);
    }

    // epilogue: transpose C through wave-private LDS scratch; per-lane top-5
    float* scr = scr_all + w * 1280;  // 64 rows x 20 (pad)
#pragma unroll
    for (int jj = 0; jj < 4; ++jj) {
      int colg = jbase + wc + jj * 16 + (l & 15);
      int cc = colg < NT ? colg : NT - 1;
      float t2v = t2g[cc];
      bool valid = colg < NT;
#pragma unroll
      for (int i = 0; i < 4; ++i)
#pragma unroll
        for (int r = 0; r < 4; ++r) {
          float sc = valid ? fmaf(-2.f, acc[i][jj][r], t2v) : FLT_MAX;
          int rowl = i * 16 + ((l >> 4) << 2) + r;
          scr[rowl * 20 + (l & 15)] = sc;
        }
      int cbg = jbase + wc + jj * 16;
#pragma unroll
      for (int c4 = 0; c4 < 4; ++c4) {
        f32x4 rv = *(const f32x4*)(scr + l * 20 + c4 * 4);
#pragma unroll
        for (int c = 0; c < 4; ++c) ins5(tv, tix, rv[c], cbg + c4 * 4 + c);
      }
    }
  }

  // cross-wave merge: waves (0,1) share rows 0-63, (2,3) rows 64-127
  __syncthreads();
  float* ms = scr_all;
  int* msi = (int*)scr_all + 640;
  if (w & 1) {
    int rid = wr + l;
#pragma unroll
    for (int s = 0; s < KTOP; ++s) { ms[rid * 5 + s] = tv[s]; msi[rid * 5 + s] = tix[s]; }
  }
  __syncthreads();
  if (!(w & 1)) {
    int rid = wr + l;
    float ov[KTOP]; int oi[KTOP];
#pragma unroll
    for (int s = 0; s < KTOP; ++s) { ov[s] = ms[rid * 5 + s]; oi[s] = msi[rid * 5 + s]; }
    merge5(tv, tix, ov, oi);
    int q = q0 + rid;
    // u8 local index: block covers <=2 tiles = 256 t's starting at blockBase.
    // FLT_MAX sentinel entries may carry garbage bytes - never selected.
    const int blockBase = (chunk * NTPC + tstart) * TTILE;
    size_t base = ((size_t)q * (NCH * NSUB) + (chunk * NSUB + tsub)) * KTOP;
#pragma unroll
    for (int s = 0; s < KTOP; ++s) {
      pvals[base + s] = tv[s];
      pidx8[base + s] = (unsigned char)(tix[s] - blockBase);
    }
  }
}

// ---------------- final merge: one wave per query, 2560 candidates -> 5 ------
__global__ __launch_bounds__(256) void knn_merge(
    const float* __restrict__ pvals, const unsigned char* __restrict__ pidx8,
    const float* __restrict__ x2, const int* __restrict__ labels,
    float* __restrict__ out) {
  const int M = NCH * NSUB * KTOP;  // 2560
  int q = (blockIdx.x * 256 + threadIdx.x) >> 6;
  int l = threadIdx.x & 63;
  if (q >= NQ) return;
  float tv[KTOP]; int tix[KTOP];
#pragma unroll
  for (int s = 0; s < KTOP; ++s) { tv[s] = FLT_MAX; tix[s] = 0x7FFFFFFF; }
  size_t base = (size_t)q * M;
#pragma unroll 1
  for (int m = l; m < M; m += 64) {
    int cs = m / KTOP;               // candidate-slot = chunk*8 + tsub
    int ch = cs >> 3, ts = cs & 7;
    int gb = (ch * NTPC + tsub_start(ts)) * TTILE;
    ins5(tv, tix, pvals[base + m], gb + (int)pidx8[base + m]);
  }
#pragma unroll
  for (int d = 32; d >= 1; d >>= 1) {
    float ov[KTOP]; int oi[KTOP];
#pragma unroll
    for (int s = 0; s < KTOP; ++s) {
      ov[s] = __shfl_down(tv[s], d, 64);
      oi[s] = __shfl_down(tix[s], d, 64);
    }
    merge5(tv, tix, ov, oi);
  }
  if (l == 0) {
    float xq = x2[q];
#pragma unroll
    for (int s = 0; s < KTOP; ++s) {
      float d2 = tv[s] + xq;
      d2 = d2 > 0.f ? d2 : 0.f;
      out[(size_t)q * KTOP + s] = sqrtf(d2);                         // topk_dists [Q,K]
      out[(size_t)NQ * KTOP + (size_t)q * KTOP + s] = (float)tix[s]; // topk_inds [Q,K]
      out[(size_t)2 * NQ * KTOP + (size_t)s * NQ + q] =
          (float)labels[tix[s]];                                      // pred [K,Q]
    }
  }
}

extern "C" void kernel_launch(void* const* d_in, const int* in_sizes, int n_in,
                              void* d_out, int out_size, void* d_ws, size_t ws_size,
                              hipStream_t stream) {
  const float* x = (const float*)d_in[0];
  const float* T = (const float*)d_in[1];
  const int* labels = (const int*)d_in[2];
  float* out = (float*)d_out;
  char* ws = (char*)d_ws;

  // ws layout (bytes), total 235,814,912 (= R4's proven ~235.8 MB footprint)
  float* t2   = (float*)(ws + 0);               // 400,000
  float* x2   = (float*)(ws + 401408);          // 8,192
  short* xhi  = (short*)(ws + 409600);          // 2,097,152
  short* xmid = (short*)(ws + 2506752);         // 2,097,152
  short* thi  = (short*)(ws + 4603904);         // 102,498,304
  short* tmid = (short*)(ws + 107102208);       // 102,498,304
  float* pvals = (float*)(ws + 209600512);      // 20,971,520
  unsigned char* pidx8 = (unsigned char*)(ws + 230572032); // 5,242,880 (end 235,814,912)

  hipMemsetAsync(ws, 0, 409600, stream);        // zero t2/x2 for atomic norms

  convert_kernel<<<CV_TBLKS + CV_XBLKS, 256, 0, stream>>>(
      x, T, xhi, xmid, thi, tmid, t2, x2);

  knn_mfma<<<QBLKS * NSUB * NCH, 256, 0, stream>>>(
      xhi, xmid, thi, tmid, t2, pvals, pidx8);

  knn_merge<<<(NQ * 64 + 255) / 256, 256, 0, stream>>>(pvals, pidx8, x2, labels, out);
}

// Round 2
// 1010.063 us; speedup vs baseline: 2.3798x; 2.3798x over previous
//
#include <hip/hip_runtime.h>
#include <float.h>
#include <math.h>

#define NQ 2048
#define NT 100000
#define DIM 512
#define KTOP 5
#define QTILE 128
#define TTILE 128
#define NTPC 13             // t-tiles per chunk
#define CHUNK (NTPC*TTILE)  // 1664
#define NCH 64              // chunk id space; 8 chunks per XCD
#define TBLKS 782           // ceil(NT/128) -> valid 128-row t-tile blocks
#define TPAD (TBLKS*128)    // 100096
#define QBLKS 16            // NQ/128
#define NSUB 4              // t-sub-blocks per chunk (tiles {4,3,3,3})
#define CV_TBLKS (TBLKS*16) // 12512 convert tasks for T
#define CV_XBLKS ((NQ/128)*16) // 256 convert tasks for x

typedef float f32x4 __attribute__((ext_vector_type(4)));
typedef short s16x8 __attribute__((ext_vector_type(8)));
typedef unsigned int u32;

__device__ __forceinline__ bool lt_pair(float v1, int i1, float v2, int i2) {
  return v1 < v2 || (v1 == v2 && i1 < i2);
}

__device__ __forceinline__ void ins5(float* tv, int* tix, float sc, int idx) {
  if (lt_pair(sc, idx, tv[4], tix[4])) {
    tv[4] = sc; tix[4] = idx;
#pragma unroll
    for (int p = 4; p > 0; --p)
      if (lt_pair(tv[p], tix[p], tv[p - 1], tix[p - 1])) {
        float tf = tv[p]; tv[p] = tv[p - 1]; tv[p - 1] = tf;
        int tn = tix[p]; tix[p] = tix[p - 1]; tix[p - 1] = tn;
      }
  }
}

__device__ __forceinline__ void merge5(float* av, int* ai, const float* bv, const int* bi) {
  float nv[5]; int ni[5];
#pragma unroll
  for (int s = 0; s < 5; ++s) {
    if (lt_pair(av[s], ai[s], bv[4 - s], bi[4 - s])) { nv[s] = av[s]; ni[s] = ai[s]; }
    else { nv[s] = bv[4 - s]; ni[s] = bi[4 - s]; }
  }
#pragma unroll
  for (int a = 0; a < 5; ++a)
#pragma unroll
    for (int b = 0; b < 4 - a; ++b)
      if (lt_pair(nv[b + 1], ni[b + 1], nv[b], ni[b])) {
        float tf = nv[b]; nv[b] = nv[b + 1]; nv[b + 1] = tf;
        int tn = ni[b]; ni[b] = ni[b + 1]; ni[b + 1] = tn;
      }
#pragma unroll
  for (int s = 0; s < 5; ++s) { av[s] = nv[s]; ai[s] = ni[s]; }
}

// ---------------- convert: fp32 -> frag-major (hi,mid) bf16, LDS-transposed ----
// One block per (src, blk128, kbi): reads 128 rows x 32 cols fp32 (coalesced
// 128B row segments), converts, transposes to frag order in LDS, writes one
// contiguous 8KB slice per array (fully coalesced: 4096 shorts = 256 thr x 16).
// Norms via atomicAdd of per-(row,kbi) partials (t2/x2 zeroed by memsetAsync).
__global__ __launch_bounds__(256) void convert_kernel(
    const float* __restrict__ x, const float* __restrict__ T,
    short* __restrict__ xhi, short* __restrict__ xmid,
    short* __restrict__ thi, short* __restrict__ tmid,
    float* __restrict__ t2, float* __restrict__ x2) {
  __shared__ short lh[4096];
  __shared__ short lm[4096];
  const int bid = blockIdx.x;
  const bool isT = bid < CV_TBLKS;
  const int task = isT ? bid : bid - CV_TBLKS;
  const int blk = task >> 4, kbi = task & 15;
  const float* src = isT ? T : x;
  short* dhi = isT ? thi : xhi;
  short* dmid = isT ? tmid : xmid;
  float* nrm = isT ? t2 : x2;
  const int nsrc = isT ? NT : NQ;

  const int t = threadIdx.x;
  const int rr = t >> 1, half = t & 1;
  const int grow = blk * 128 + rr;
  const int rs = grow < nsrc ? grow : nsrc - 1;
  const float* p = src + (size_t)rs * DIM + kbi * 32 + half * 16;
  f32x4 v[4];
#pragma unroll
  for (int i = 0; i < 4; ++i) v[i] = ((const f32x4*)p)[i];

  float ss = 0.f;
#pragma unroll
  for (int g = 0; g < 2; ++g) {
    s16x8 hv, mv;
#pragma unroll
    for (int e = 0; e < 8; ++e) {
      int i = g * 8 + e;
      float f = v[i >> 2][i & 3];
      ss = fmaf(f, f, ss);
      u32 u = __builtin_bit_cast(u32, f);
      u32 r1 = u + 0x7FFFu + ((u >> 16) & 1u);        // RNE to bf16
      float resid = f - __builtin_bit_cast(float, r1 & 0xFFFF0000u);
      u32 u2 = __builtin_bit_cast(u32, resid);
      u32 r2 = u2 + 0x7FFFu + ((u2 >> 16) & 1u);
      hv[e] = (short)(r1 >> 16);
      mv[e] = (short)(r2 >> 16);
    }
    // frag unit: tile = rr>>4, quad = half*2+g, m = rr&15
    int unit = (rr >> 4) * 64 + (half * 2 + g) * 16 + (rr & 15);
    *(s16x8*)(lh + unit * 8) = hv;
    *(s16x8*)(lm + unit * 8) = mv;
  }
  ss += __shfl_xor(ss, 1, 64);       // pair (t, t^1) share a row
  if (half == 0 && grow < nsrc) atomicAdd(nrm + grow, ss);

  __syncthreads();
  // slice = 4096 shorts per array; thread t copies shorts [t*16, t*16+16)
  size_t obase = ((size_t)(blk * 16 + kbi)) * 4096 + t * 16;
  *(s16x8*)(dhi + obase)      = *(const s16x8*)(lh + t * 16);
  *(s16x8*)(dhi + obase + 8)  = *(const s16x8*)(lh + t * 16 + 8);
  *(s16x8*)(dmid + obase)     = *(const s16x8*)(lm + t * 16);
  *(s16x8*)(dmid + obase + 8) = *(const s16x8*)(lm + t * 16 + 8);
}

// pointer-bump fragment load: 4 x 16B per array at i*1024B immediates
// (fits the 13-bit signed global offset), then advance all pointers by one
// kbi slab (512 s16x8 units = 8192 B). Replaces per-step 64-bit base math.
__device__ __forceinline__ void load_frags(
    const s16x8*& pah, const s16x8*& pam, const s16x8*& pbh, const s16x8*& pbm,
    s16x8* ah, s16x8* am, s16x8* bh, s16x8* bm) {
#pragma unroll
  for (int i = 0; i < 4; ++i) {
    ah[i] = pah[i * 64];
    am[i] = pam[i * 64];
    bh[i] = pbh[i * 64];
    bm[i] = pbm[i * 64];
  }
  pah += 512; pam += 512; pbh += 512; pbm += 512;
}

__device__ __forceinline__ void do_mfma(const s16x8* ah, const s16x8* am,
                                        const s16x8* bh, const s16x8* bm,
                                        f32x4 acc[4][4]) {
  __builtin_amdgcn_s_setprio(1);   // barrier-free loop: waves drift out of
                                   // phase -> scheduler can favor MFMA wave
#pragma unroll
  for (int j = 0; j < 4; ++j)
#pragma unroll
    for (int i = 0; i < 4; ++i) {
      acc[i][j] = __builtin_amdgcn_mfma_f32_16x16x32_bf16(ah[i], bh[j], acc[i][j], 0, 0, 0);
      acc[i][j] = __builtin_amdgcn_mfma_f32_16x16x32_bf16(ah[i], bm[j], acc[i][j], 0, 0, 0);
      acc[i][j] = __builtin_amdgcn_mfma_f32_16x16x32_bf16(am[i], bh[j], acc[i][j], 0, 0, 0);
    }
  __builtin_amdgcn_s_setprio(0);
}

// ---------------- main: barrier-free K-loop, direct global->VGPR fragments ----
// Grid 4096: bid = xcd + 8*(inner + 64*chunkHigh); inner = tsub*16 + qblk.
// Per XCD the 64 co-resident blocks (2/CU x 32 CU) = 16 qblk x 4 tsub of ONE
// chunk -> B working set 13 tiles x 256KB = 3.3 MB, fits the 4 MB XCD L2.
// NOTE (R1 lesson): (256,3) forces VGPR cap 84 -> fragment spills (WRITE_SIZE
// 45MB->4.3GB). acc(64)+dbuf frags(128)+misc ~= 220 regs; 3 waves/SIMD needs
// <=170. Keep (256,2).
__global__ __launch_bounds__(256, 2) void knn_mfma(
    const short* __restrict__ xhi, const short* __restrict__ xmid,
    const short* __restrict__ thi, const short* __restrict__ tmid,
    const float* __restrict__ t2g,
    float* __restrict__ pvals, int* __restrict__ pidx) {
  __shared__ float scr_all[4 * 1280];  // per-wave epilogue scratch (20 KB)

  const int tid = threadIdx.x;
  const int w = tid >> 6;
  const int l = tid & 63;
  const int bid = blockIdx.x;
  const int rest = bid >> 3;
  const int inner = rest & 63;
  const int chunk = (bid & 7) + 8 * (rest >> 6);
  const int qblk = inner & 15;
  const int tsub = inner >> 4;                 // 0..3
  const int tstart = (13 * tsub + 3) >> 2;     // {0,4,7,10}
  const int tend = (13 * (tsub + 1) + 3) >> 2; // {4,7,10,13}
  const int q0 = qblk * QTILE;
  const int wr = (w >> 1) * 64;
  const int wc = (w & 1) * 64;
  const int arow = wr >> 4;
  const int bcol = wc >> 4;

  float tv[KTOP]; int tix[KTOP];
#pragma unroll
  for (int s = 0; s < KTOP; ++s) { tv[s] = FLT_MAX; tix[s] = 0x7FFFFFFF; }

#pragma unroll 1
  for (int tt = tstart; tt < tend; ++tt) {
    const int bblk = chunk * NTPC + tt;
    if (bblk >= TBLKS) continue;   // fully past NT: partials stay FLT_MAX
    const int jbase = bblk * TTILE;
    f32x4 acc[4][4];
#pragma unroll
    for (int i = 0; i < 4; ++i)
#pragma unroll
      for (int j = 0; j < 4; ++j) acc[i][j] = (f32x4){0.f, 0.f, 0.f, 0.f};

    s16x8 ah0[4], am0[4], bh0[4], bm0[4];
    s16x8 ah1[4], am1[4], bh1[4], bm1[4];
    // frag pointers in s16x8 units; kbi stride = 512 units (8192 B)
    const size_t ao = (size_t)(qblk * 16) * 512 + (size_t)(arow * 64 + l);
    const size_t bo = (size_t)(bblk * 16) * 512 + (size_t)(bcol * 64 + l);
    const s16x8* pah = (const s16x8*)xhi + ao;
    const s16x8* pam = (const s16x8*)xmid + ao;
    const s16x8* pbh = (const s16x8*)thi + bo;
    const s16x8* pbm = (const s16x8*)tmid + bo;

    load_frags(pah, pam, pbh, pbm, ah0, am0, bh0, bm0);
#pragma unroll 1
    for (int step = 0; step < 8; ++step) {
      load_frags(pah, pam, pbh, pbm, ah1, am1, bh1, bm1);
      do_mfma(ah0, am0, bh0, bm0, acc);
      if (step < 7)
        load_frags(pah, pam, pbh, pbm, ah0, am0, bh0, bm0);
      do_mfma(ah1, am1, bh1, bm1, acc);
    }

    // epilogue: transpose C through wave-private LDS scratch; per-lane top-5
    float* scr = scr_all + w * 1280;  // 64 rows x 20 (pad)
#pragma unroll
    for (int jj = 0; jj < 4; ++jj) {
      int colg = jbase + wc + jj * 16 + (l & 15);
      int cc = colg < NT ? colg : NT - 1;
      float t2v = t2g[cc];
      bool valid = colg < NT;
#pragma unroll
      for (int i = 0; i < 4; ++i)
#pragma unroll
        for (int r = 0; r < 4; ++r) {
          float sc = valid ? fmaf(-2.f, acc[i][jj][r], t2v) : FLT_MAX;
          int rowl = i * 16 + ((l >> 4) << 2) + r;
          scr[rowl * 20 + (l & 15)] = sc;
        }
      int cbg = jbase + wc + jj * 16;
#pragma unroll
      for (int c4 = 0; c4 < 4; ++c4) {
        f32x4 rv = *(const f32x4*)(scr + l * 20 + c4 * 4);
#pragma unroll
        for (int c = 0; c < 4; ++c) ins5(tv, tix, rv[c], cbg + c4 * 4 + c);
      }
    }
  }

  // cross-wave merge: waves (0,1) share rows 0-63, (2,3) rows 64-127
  __syncthreads();
  float* ms = scr_all;
  int* msi = (int*)scr_all + 640;
  if (w & 1) {
    int rid = wr + l;
#pragma unroll
    for (int s = 0; s < KTOP; ++s) { ms[rid * 5 + s] = tv[s]; msi[rid * 5 + s] = tix[s]; }
  }
  __syncthreads();
  if (!(w & 1)) {
    int rid = wr + l;
    float ov[KTOP]; int oi[KTOP];
#pragma unroll
    for (int s = 0; s < KTOP; ++s) { ov[s] = ms[rid * 5 + s]; oi[s] = msi[rid * 5 + s]; }
    merge5(tv, tix, ov, oi);
    int q = q0 + rid;
    size_t base = ((size_t)q * (NCH * NSUB) + (chunk * NSUB + tsub)) * KTOP;
#pragma unroll
    for (int s = 0; s < KTOP; ++s) { pvals[base + s] = tv[s]; pidx[base + s] = tix[s]; }
  }
}

// ---------------- final merge: one wave per query, 1280 candidates -> 5 ------
__global__ __launch_bounds__(256) void knn_merge(
    const float* __restrict__ pvals, const int* __restrict__ pidx,
    const float* __restrict__ x2, const int* __restrict__ labels,
    float* __restrict__ out) {
  const int M = NCH * NSUB * KTOP;  // 1280
  int q = (blockIdx.x * 256 + threadIdx.x) >> 6;
  int l = threadIdx.x & 63;
  if (q >= NQ) return;
  float tv[KTOP]; int tix[KTOP];
#pragma unroll
  for (int s = 0; s < KTOP; ++s) { tv[s] = FLT_MAX; tix[s] = 0x7FFFFFFF; }
  size_t base = (size_t)q * M;
#pragma unroll 1
  for (int m = l; m < M; m += 64) ins5(tv, tix, pvals[base + m], pidx[base + m]);
#pragma unroll
  for (int d = 32; d >= 1; d >>= 1) {
    float ov[KTOP]; int oi[KTOP];
#pragma unroll
    for (int s = 0; s < KTOP; ++s) {
      ov[s] = __shfl_down(tv[s], d, 64);
      oi[s] = __shfl_down(tix[s], d, 64);
    }
    merge5(tv, tix, ov, oi);
  }
  if (l == 0) {
    float xq = x2[q];
#pragma unroll
    for (int s = 0; s < KTOP; ++s) {
      float d2 = tv[s] + xq;
      d2 = d2 > 0.f ? d2 : 0.f;
      out[(size_t)q * KTOP + s] = sqrtf(d2);                         // topk_dists [Q,K]
      out[(size_t)NQ * KTOP + (size_t)q * KTOP + s] = (float)tix[s]; // topk_inds [Q,K]
      out[(size_t)2 * NQ * KTOP + (size_t)s * NQ + q] =
          (float)labels[tix[s]];                                      // pred [K,Q]
    }
  }
}

extern "C" void kernel_launch(void* const* d_in, const int* in_sizes, int n_in,
                              void* d_out, int out_size, void* d_ws, size_t ws_size,
                              hipStream_t stream) {
  const float* x = (const float*)d_in[0];
  const float* T = (const float*)d_in[1];
  const int* labels = (const int*)d_in[2];
  float* out = (float*)d_out;
  char* ws = (char*)d_ws;

  // ws layout (bytes), total ~230.6 MB (R4's proven footprint was ~235.8 MB)
  float* t2   = (float*)(ws + 0);               // 400,000
  float* x2   = (float*)(ws + 401408);          // 8,192
  short* xhi  = (short*)(ws + 409600);          // 2,097,152
  short* xmid = (short*)(ws + 2506752);         // 2,097,152
  short* thi  = (short*)(ws + 4603904);         // 102,498,304
  short* tmid = (short*)(ws + 107102208);       // 102,498,304
  float* pvals = (float*)(ws + 209600512);      // 10,485,760
  int*   pidx  = (int*)(ws + 220086272);        // 10,485,760 (end 230,572,032)

  hipMemsetAsync(ws, 0, 409600, stream);        // zero t2/x2 for atomic norms

  convert_kernel<<<CV_TBLKS + CV_XBLKS, 256, 0, stream>>>(
      x, T, xhi, xmid, thi, tmid, t2, x2);

  knn_mfma<<<QBLKS * NSUB * NCH, 256, 0, stream>>>(
      xhi, xmid, thi, tmid, t2, pvals, pidx);

  knn_merge<<<(NQ * 64 + 255) / 256, 256, 0, stream>>>(pvals, pidx, x2, labels, out);
}

// Round 3
// 987.515 us; speedup vs baseline: 2.4341x; 1.0228x over previous
//
#include <hip/hip_runtime.h>
#include <float.h>
#include <math.h>

#define NQ 2048
#define NT 100000
#define DIM 512
#define KTOP 5
#define QTILE 128
#define TTILE 128
#define NTPC 13             // t-tiles per chunk
#define CHUNK (NTPC*TTILE)  // 1664
#define NCH 64              // chunk id space; 8 chunks per XCD
#define TBLKS 782           // ceil(NT/128) -> valid 128-row t-tile blocks
#define TPAD (TBLKS*128)    // 100096
#define QBLKS 16            // NQ/128
#define NSUB 6              // t-sub-blocks per chunk (tiles {3,2,2,2,2,2})
#define CV_TBLKS (TBLKS*16) // 12512 convert tasks for T
#define CV_XBLKS ((NQ/128)*16) // 256 convert tasks for x

typedef float f32x4 __attribute__((ext_vector_type(4)));
typedef short s16x8 __attribute__((ext_vector_type(8)));
typedef unsigned int u32;
typedef unsigned short u16;

__device__ __forceinline__ int tsub_start(int ts) { return (13 * ts + 5) / 6; }

__device__ __forceinline__ bool lt_pair(float v1, int i1, float v2, int i2) {
  return v1 < v2 || (v1 == v2 && i1 < i2);
}

__device__ __forceinline__ void ins5(float* tv, int* tix, float sc, int idx) {
  if (lt_pair(sc, idx, tv[4], tix[4])) {
    tv[4] = sc; tix[4] = idx;
#pragma unroll
    for (int p = 4; p > 0; --p)
      if (lt_pair(tv[p], tix[p], tv[p - 1], tix[p - 1])) {
        float tf = tv[p]; tv[p] = tv[p - 1]; tv[p - 1] = tf;
        int tn = tix[p]; tix[p] = tix[p - 1]; tix[p - 1] = tn;
      }
  }
}

__device__ __forceinline__ void merge5(float* av, int* ai, const float* bv, const int* bi) {
  float nv[5]; int ni[5];
#pragma unroll
  for (int s = 0; s < 5; ++s) {
    if (lt_pair(av[s], ai[s], bv[4 - s], bi[4 - s])) { nv[s] = av[s]; ni[s] = ai[s]; }
    else { nv[s] = bv[4 - s]; ni[s] = bi[4 - s]; }
  }
#pragma unroll
  for (int a = 0; a < 5; ++a)
#pragma unroll
    for (int b = 0; b < 4 - a; ++b)
      if (lt_pair(nv[b + 1], ni[b + 1], nv[b], ni[b])) {
        float tf = nv[b]; nv[b] = nv[b + 1]; nv[b + 1] = tf;
        int tn = ni[b]; ni[b] = ni[b + 1]; ni[b + 1] = tn;
      }
#pragma unroll
  for (int s = 0; s < 5; ++s) { av[s] = nv[s]; ai[s] = ni[s]; }
}

// ---------------- convert: fp32 -> frag-major (hi,mid) bf16, LDS-transposed ----
// One block per (src, blk128, kbi): reads 128 rows x 32 cols fp32 (coalesced
// 128B row segments), converts, transposes to frag order in LDS, writes one
// contiguous 8KB slice per array (fully coalesced: 4096 shorts = 256 thr x 16).
// Norms via atomicAdd of per-(row,kbi) partials (t2/x2 zeroed by memsetAsync).
__global__ __launch_bounds__(256) void convert_kernel(
    const float* __restrict__ x, const float* __restrict__ T,
    short* __restrict__ xhi, short* __restrict__ xmid,
    short* __restrict__ thi, short* __restrict__ tmid,
    float* __restrict__ t2, float* __restrict__ x2) {
  __shared__ short lh[4096];
  __shared__ short lm[4096];
  const int bid = blockIdx.x;
  const bool isT = bid < CV_TBLKS;
  const int task = isT ? bid : bid - CV_TBLKS;
  const int blk = task >> 4, kbi = task & 15;
  const float* src = isT ? T : x;
  short* dhi = isT ? thi : xhi;
  short* dmid = isT ? tmid : xmid;
  float* nrm = isT ? t2 : x2;
  const int nsrc = isT ? NT : NQ;

  const int t = threadIdx.x;
  const int rr = t >> 1, half = t & 1;
  const int grow = blk * 128 + rr;
  const int rs = grow < nsrc ? grow : nsrc - 1;
  const float* p = src + (size_t)rs * DIM + kbi * 32 + half * 16;
  f32x4 v[4];
#pragma unroll
  for (int i = 0; i < 4; ++i) v[i] = ((const f32x4*)p)[i];

  float ss = 0.f;
#pragma unroll
  for (int g = 0; g < 2; ++g) {
    s16x8 hv, mv;
#pragma unroll
    for (int e = 0; e < 8; ++e) {
      int i = g * 8 + e;
      float f = v[i >> 2][i & 3];
      ss = fmaf(f, f, ss);
      u32 u = __builtin_bit_cast(u32, f);
      u32 r1 = u + 0x7FFFu + ((u >> 16) & 1u);        // RNE to bf16
      float resid = f - __builtin_bit_cast(float, r1 & 0xFFFF0000u);
      u32 u2 = __builtin_bit_cast(u32, resid);
      u32 r2 = u2 + 0x7FFFu + ((u2 >> 16) & 1u);
      hv[e] = (short)(r1 >> 16);
      mv[e] = (short)(r2 >> 16);
    }
    // frag unit: tile = rr>>4, quad = half*2+g, m = rr&15
    int unit = (rr >> 4) * 64 + (half * 2 + g) * 16 + (rr & 15);
    *(s16x8*)(lh + unit * 8) = hv;
    *(s16x8*)(lm + unit * 8) = mv;
  }
  ss += __shfl_xor(ss, 1, 64);       // pair (t, t^1) share a row
  if (half == 0 && grow < nsrc) atomicAdd(nrm + grow, ss);

  __syncthreads();
  // slice = 4096 shorts per array; thread t copies shorts [t*16, t*16+16)
  size_t obase = ((size_t)(blk * 16 + kbi)) * 4096 + t * 16;
  *(s16x8*)(dhi + obase)      = *(const s16x8*)(lh + t * 16);
  *(s16x8*)(dhi + obase + 8)  = *(const s16x8*)(lh + t * 16 + 8);
  *(s16x8*)(dmid + obase)     = *(const s16x8*)(lm + t * 16);
  *(s16x8*)(dmid + obase + 8) = *(const s16x8*)(lm + t * 16 + 8);
}

// single-buffered fragment load: u32 element offsets from SGPR bases
// (saddr + 32-bit voffset form; i*1024B folds into the 13-bit inst offset).
__device__ __forceinline__ void load_frags(
    const s16x8* __restrict__ xh8, const s16x8* __restrict__ xm8,
    const s16x8* __restrict__ th8, const s16x8* __restrict__ tm8,
    u32 offA, u32 offB,
    s16x8* ah, s16x8* am, s16x8* bh, s16x8* bm) {
#pragma unroll
  for (int i = 0; i < 4; ++i) {
    ah[i] = xh8[offA + i * 64];
    am[i] = xm8[offA + i * 64];
    bh[i] = th8[offB + i * 64];
    bm[i] = tm8[offB + i * 64];
  }
}

__device__ __forceinline__ void do_mfma(const s16x8* ah, const s16x8* am,
                                        const s16x8* bh, const s16x8* bm,
                                        f32x4 acc[4][4]) {
  __builtin_amdgcn_s_setprio(1);   // barrier-free loop: waves drift out of
                                   // phase -> scheduler can favor MFMA wave
#pragma unroll
  for (int j = 0; j < 4; ++j)
#pragma unroll
    for (int i = 0; i < 4; ++i) {
      acc[i][j] = __builtin_amdgcn_mfma_f32_16x16x32_bf16(ah[i], bh[j], acc[i][j], 0, 0, 0);
      acc[i][j] = __builtin_amdgcn_mfma_f32_16x16x32_bf16(ah[i], bm[j], acc[i][j], 0, 0, 0);
      acc[i][j] = __builtin_amdgcn_mfma_f32_16x16x32_bf16(am[i], bh[j], acc[i][j], 0, 0, 0);
    }
  __builtin_amdgcn_s_setprio(0);
}

// ---------------- main: barrier-free K-loop, direct global->VGPR fragments ----
// Grid 6144: bid = xcd + 8*(inner + 96*chunkHigh); inner = tsub*16 + qblk
// (96 ids = 16 qblk x 6 tsub). Per XCD the 96 co-resident blocks (3/CU x 32 CU)
// cover ONE chunk -> B working set 13 tiles x 256KB = 3.3 MB <= 4 MB XCD L2.
// R1 lesson: dbuf frags(128)+acc(64) ~= 190 regs -> (256,3) spills (cap ~170).
// R2 lesson: pointer-bump/setprio null at 2 waves/SIMD; structure is the limit.
// This round: SINGLE-buffered frags (64) + acc(64) + ~35 misc ~= 163 <= 170 ->
// 3 waves/SIMD without spill; TLP replaces the lost within-wave prefetch.
__global__ __launch_bounds__(256, 3) void knn_mfma(
    const short* __restrict__ xhi, const short* __restrict__ xmid,
    const short* __restrict__ thi, const short* __restrict__ tmid,
    const float* __restrict__ t2g,
    float* __restrict__ pvals, u16* __restrict__ pidx16) {
  __shared__ float scr_all[4 * 1280];  // per-wave epilogue scratch (20 KB)

  const int tid = threadIdx.x;
  const int w = tid >> 6;
  const int l = tid & 63;
  const int bid = blockIdx.x;
  const u32 rest = (u32)bid >> 3;
  const int inner = (int)(rest % 96u);
  const int chunk = (bid & 7) + 8 * (int)(rest / 96u);
  const int qblk = inner & 15;
  const int tsub = inner >> 4;                 // 0..5
  const int tstart = tsub_start(tsub);
  const int tend = tsub_start(tsub + 1);
  const int q0 = qblk * QTILE;
  const int wr = (w >> 1) * 64;
  const int wc = (w & 1) * 64;
  const int arow = wr >> 4;
  const int bcol = wc >> 4;

  const s16x8* xh8 = (const s16x8*)xhi;
  const s16x8* xm8 = (const s16x8*)xmid;
  const s16x8* th8 = (const s16x8*)thi;
  const s16x8* tm8 = (const s16x8*)tmid;

  float tv[KTOP]; int tix[KTOP];
#pragma unroll
  for (int s = 0; s < KTOP; ++s) { tv[s] = FLT_MAX; tix[s] = 0x7FFFFFFF; }

#pragma unroll 1
  for (int tt = tstart; tt < tend; ++tt) {
    const int bblk = chunk * NTPC + tt;
    if (bblk >= TBLKS) continue;   // fully past NT: partials stay FLT_MAX
    const int jbase = bblk * TTILE;
    f32x4 acc[4][4];
#pragma unroll
    for (int i = 0; i < 4; ++i)
#pragma unroll
      for (int j = 0; j < 4; ++j) acc[i][j] = (f32x4){0.f, 0.f, 0.f, 0.f};

    // element offsets (s16x8 units); kbi stride = 512 units (8192 B)
    u32 offA = (u32)(qblk * 16) * 512u + (u32)(arow * 64 + l);
    u32 offB = (u32)(bblk * 16) * 512u + (u32)(bcol * 64 + l);
    s16x8 ah[4], am[4], bh[4], bm[4];
#pragma unroll 1
    for (int kbi = 0; kbi < 16; ++kbi) {
      load_frags(xh8, xm8, th8, tm8, offA, offB, ah, am, bh, bm);
      offA += 512; offB += 512;
      do_mfma(ah, am, bh, bm, acc);
    }

    // epilogue: transpose C through wave-private LDS scratch; per-lane top-5
    float* scr = scr_all + w * 1280;  // 64 rows x 20 (pad)
#pragma unroll
    for (int jj = 0; jj < 4; ++jj) {
      int colg = jbase + wc + jj * 16 + (l & 15);
      int cc = colg < NT ? colg : NT - 1;
      float t2v = t2g[cc];
      bool valid = colg < NT;
#pragma unroll
      for (int i = 0; i < 4; ++i)
#pragma unroll
        for (int r = 0; r < 4; ++r) {
          float sc = valid ? fmaf(-2.f, acc[i][jj][r], t2v) : FLT_MAX;
          int rowl = i * 16 + ((l >> 4) << 2) + r;
          scr[rowl * 20 + (l & 15)] = sc;
        }
      int cbg = jbase + wc + jj * 16;
#pragma unroll
      for (int c4 = 0; c4 < 4; ++c4) {
        f32x4 rv = *(const f32x4*)(scr + l * 20 + c4 * 4);
#pragma unroll
        for (int c = 0; c < 4; ++c) ins5(tv, tix, rv[c], cbg + c4 * 4 + c);
      }
    }
  }

  // cross-wave merge: waves (0,1) share rows 0-63, (2,3) rows 64-127
  __syncthreads();
  float* ms = scr_all;
  int* msi = (int*)scr_all + 640;
  if (w & 1) {
    int rid = wr + l;
#pragma unroll
    for (int s = 0; s < KTOP; ++s) { ms[rid * 5 + s] = tv[s]; msi[rid * 5 + s] = tix[s]; }
  }
  __syncthreads();
  if (!(w & 1)) {
    int rid = wr + l;
    float ov[KTOP]; int oi[KTOP];
#pragma unroll
    for (int s = 0; s < KTOP; ++s) { ov[s] = ms[rid * 5 + s]; oi[s] = msi[rid * 5 + s]; }
    merge5(tv, tix, ov, oi);
    int q = q0 + rid;
    // u16 local index: block covers <=3 tiles = 384 t's from blockBase.
    // FLT_MAX sentinel entries may carry garbage offsets - never selected.
    const int blockBase = (chunk * NTPC + tstart) * TTILE;
    size_t base = ((size_t)q * (NCH * NSUB) + (chunk * NSUB + tsub)) * KTOP;
#pragma unroll
    for (int s = 0; s < KTOP; ++s) {
      pvals[base + s] = tv[s];
      pidx16[base + s] = (u16)(tix[s] - blockBase);
    }
  }
}

// ---------------- final merge: one wave per query, 1920 candidates -> 5 ------
__global__ __launch_bounds__(256) void knn_merge(
    const float* __restrict__ pvals, const u16* __restrict__ pidx16,
    const float* __restrict__ x2, const int* __restrict__ labels,
    float* __restrict__ out) {
  const int M = NCH * NSUB * KTOP;  // 1920
  int q = (blockIdx.x * 256 + threadIdx.x) >> 6;
  int l = threadIdx.x & 63;
  if (q >= NQ) return;
  float tv[KTOP]; int tix[KTOP];
#pragma unroll
  for (int s = 0; s < KTOP; ++s) { tv[s] = FLT_MAX; tix[s] = 0x7FFFFFFF; }
  size_t base = (size_t)q * M;
#pragma unroll 1
  for (int m = l; m < M; m += 64) {
    int cs = m / KTOP;               // candidate-slot = chunk*NSUB + tsub
    int ch = cs / NSUB, ts = cs % NSUB;
    int gb = (ch * NTPC + tsub_start(ts)) * TTILE;
    ins5(tv, tix, pvals[base + m], gb + (int)pidx16[base + m]);
  }
#pragma unroll
  for (int d = 32; d >= 1; d >>= 1) {
    float ov[KTOP]; int oi[KTOP];
#pragma unroll
    for (int s = 0; s < KTOP; ++s) {
      ov[s] = __shfl_down(tv[s], d, 64);
      oi[s] = __shfl_down(tix[s], d, 64);
    }
    merge5(tv, tix, ov, oi);
  }
  if (l == 0) {
    float xq = x2[q];
#pragma unroll
    for (int s = 0; s < KTOP; ++s) {
      float d2 = tv[s] + xq;
      d2 = d2 > 0.f ? d2 : 0.f;
      out[(size_t)q * KTOP + s] = sqrtf(d2);                         // topk_dists [Q,K]
      out[(size_t)NQ * KTOP + (size_t)q * KTOP + s] = (float)tix[s]; // topk_inds [Q,K]
      out[(size_t)2 * NQ * KTOP + (size_t)s * NQ + q] =
          (float)labels[tix[s]];                                      // pred [K,Q]
    }
  }
}

extern "C" void kernel_launch(void* const* d_in, const int* in_sizes, int n_in,
                              void* d_out, int out_size, void* d_ws, size_t ws_size,
                              hipStream_t stream) {
  const float* x = (const float*)d_in[0];
  const float* T = (const float*)d_in[1];
  const int* labels = (const int*)d_in[2];
  float* out = (float*)d_out;
  char* ws = (char*)d_ws;

  // ws layout (bytes), total 233,193,472 (<= proven 235.8 MB footprint)
  float* t2   = (float*)(ws + 0);               // 400,000
  float* x2   = (float*)(ws + 401408);          // 8,192
  short* xhi  = (short*)(ws + 409600);          // 2,097,152
  short* xmid = (short*)(ws + 2506752);         // 2,097,152
  short* thi  = (short*)(ws + 4603904);         // 102,498,304
  short* tmid = (short*)(ws + 107102208);       // 102,498,304 (end 209,600,512)
  float* pvals = (float*)(ws + 209600512);      // 15,728,640
  u16*   pidx16 = (u16*)(ws + 225329152);       // 7,864,320 (end 233,193,472)

  hipMemsetAsync(ws, 0, 409600, stream);        // zero t2/x2 for atomic norms

  convert_kernel<<<CV_TBLKS + CV_XBLKS, 256, 0, stream>>>(
      x, T, xhi, xmid, thi, tmid, t2, x2);

  knn_mfma<<<QBLKS * NSUB * NCH, 256, 0, stream>>>(
      xhi, xmid, thi, tmid, t2, pvals, pidx16);

  knn_merge<<<(NQ * 64 + 255) / 256, 256, 0, stream>>>(pvals, pidx16, x2, labels, out);
}

// Round 4
// 684.731 us; speedup vs baseline: 3.5105x; 1.4422x over previous
//
#include <hip/hip_runtime.h>
#include <float.h>
#include <math.h>

#define NQ 2048
#define NT 100000
#define DIM 512
#define KTOP 5
#define NCAND 16            // screening survivors per query (exact re-rank set)
#define QTILE 128
#define TTILE 128
#define NTPC 13             // t-tiles per chunk
#define NCH 64              // chunk id space; 8 chunks per XCD
#define TBLKS 782           // ceil(NT/128) -> valid 128-row t-tile blocks
#define QBLKS 16            // NQ/128
#define NSUB 6              // t-sub-blocks per chunk (tiles {3,2,2,2,2,2})
#define CV_TBLKS (TBLKS*16) // 12512 convert tasks for T
#define CV_XBLKS ((NQ/128)*16) // 256 convert tasks for x

typedef float f32x4 __attribute__((ext_vector_type(4)));
typedef short s16x8 __attribute__((ext_vector_type(8)));
typedef unsigned int u32;
typedef unsigned short u16;

__device__ __forceinline__ int tsub_start(int ts) { return (13 * ts + 5) / 6; }

__device__ __forceinline__ bool lt_pair(float v1, int i1, float v2, int i2) {
  return v1 < v2 || (v1 == v2 && i1 < i2);
}

__device__ __forceinline__ void ins5(float* tv, int* tix, float sc, int idx) {
  if (lt_pair(sc, idx, tv[4], tix[4])) {
    tv[4] = sc; tix[4] = idx;
#pragma unroll
    for (int p = 4; p > 0; --p)
      if (lt_pair(tv[p], tix[p], tv[p - 1], tix[p - 1])) {
        float tf = tv[p]; tv[p] = tv[p - 1]; tv[p - 1] = tf;
        int tn = tix[p]; tix[p] = tix[p - 1]; tix[p - 1] = tn;
      }
  }
}

__device__ __forceinline__ void merge5(float* av, int* ai, const float* bv, const int* bi) {
  float nv[5]; int ni[5];
#pragma unroll
  for (int s = 0; s < 5; ++s) {
    if (lt_pair(av[s], ai[s], bv[4 - s], bi[4 - s])) { nv[s] = av[s]; ni[s] = ai[s]; }
    else { nv[s] = bv[4 - s]; ni[s] = bi[4 - s]; }
  }
#pragma unroll
  for (int a = 0; a < 5; ++a)
#pragma unroll
    for (int b = 0; b < 4 - a; ++b)
      if (lt_pair(nv[b + 1], ni[b + 1], nv[b], ni[b])) {
        float tf = nv[b]; nv[b] = nv[b + 1]; nv[b + 1] = tf;
        int tn = ni[b]; ni[b] = ni[b + 1]; ni[b + 1] = tn;
      }
#pragma unroll
  for (int s = 0; s < 5; ++s) { av[s] = nv[s]; ai[s] = ni[s]; }
}

// ---------------- convert: fp32 -> frag-major HI bf16 only (screening) -------
// Screening is single-product bf16: error on d2 ~ +-0.3 absolute vs typical
// order-stat gaps ~5 near the minimum -> exact re-rank of top-16 is safe.
// One block per (src, blk128, kbi): reads 128 rows x 32 cols fp32, converts
// RNE, transposes to frag order in LDS, writes one contiguous 4KB slice.
__global__ __launch_bounds__(256) void convert_kernel(
    const float* __restrict__ x, const float* __restrict__ T,
    short* __restrict__ xhi, short* __restrict__ thi,
    float* __restrict__ t2, float* __restrict__ x2) {
  __shared__ short lh[4096];
  const int bid = blockIdx.x;
  const bool isT = bid < CV_TBLKS;
  const int task = isT ? bid : bid - CV_TBLKS;
  const int blk = task >> 4, kbi = task & 15;
  const float* src = isT ? T : x;
  short* dhi = isT ? thi : xhi;
  float* nrm = isT ? t2 : x2;
  const int nsrc = isT ? NT : NQ;

  const int t = threadIdx.x;
  const int rr = t >> 1, half = t & 1;
  const int grow = blk * 128 + rr;
  const int rs = grow < nsrc ? grow : nsrc - 1;
  const float* p = src + (size_t)rs * DIM + kbi * 32 + half * 16;
  f32x4 v[4];
#pragma unroll
  for (int i = 0; i < 4; ++i) v[i] = ((const f32x4*)p)[i];

  float ss = 0.f;
#pragma unroll
  for (int g = 0; g < 2; ++g) {
    s16x8 hv;
#pragma unroll
    for (int e = 0; e < 8; ++e) {
      int i = g * 8 + e;
      float f = v[i >> 2][i & 3];
      ss = fmaf(f, f, ss);
      u32 u = __builtin_bit_cast(u32, f);
      u32 r1 = u + 0x7FFFu + ((u >> 16) & 1u);        // RNE to bf16
      hv[e] = (short)(r1 >> 16);
    }
    // frag unit: tile = rr>>4, quad = half*2+g, m = rr&15
    int unit = (rr >> 4) * 64 + (half * 2 + g) * 16 + (rr & 15);
    *(s16x8*)(lh + unit * 8) = hv;
  }
  ss += __shfl_xor(ss, 1, 64);       // pair (t, t^1) share a row
  if (half == 0 && grow < nsrc) atomicAdd(nrm + grow, ss);

  __syncthreads();
  // slice = 4096 shorts; thread t copies shorts [t*16, t*16+16)
  size_t obase = ((size_t)(blk * 16 + kbi)) * 4096 + t * 16;
  *(s16x8*)(dhi + obase)     = *(const s16x8*)(lh + t * 16);
  *(s16x8*)(dhi + obase + 8) = *(const s16x8*)(lh + t * 16 + 8);
}

// ---------------- stage 1: screening GEMM (hi x hi only) --------------------
// R3 post-mortem model: kernel is vector-memory-PORT bound (per CU ~196KB/kbi
// round vs ~128B/cyc -> MfmaUtil capped ~45%). Halving bytes (no mid arrays)
// halves the wall-clock; MFMA count drops 3x (1 product instead of 3).
// Grid 6144: inner = tsub*16 + qblk (96 ids = 3 blocks/CU x 32 CU per XCD),
// all co-resident blocks of an XCD share ONE chunk of B -> L2-resident.
__global__ __launch_bounds__(256, 3) void knn_mfma(
    const short* __restrict__ xhi, const short* __restrict__ thi,
    const float* __restrict__ t2g,
    float* __restrict__ pvals, u16* __restrict__ pidx16) {
  __shared__ float scr_all[4 * 1280];  // per-wave epilogue scratch (20 KB)

  const int tid = threadIdx.x;
  const int w = tid >> 6;
  const int l = tid & 63;
  const int bid = blockIdx.x;
  const u32 rest = (u32)bid >> 3;
  const int inner = (int)(rest % 96u);
  const int chunk = (bid & 7) + 8 * (int)(rest / 96u);
  const int qblk = inner & 15;
  const int tsub = inner >> 4;                 // 0..5
  const int tstart = tsub_start(tsub);
  const int tend = tsub_start(tsub + 1);
  const int q0 = qblk * QTILE;
  const int wr = (w >> 1) * 64;
  const int wc = (w & 1) * 64;
  const int arow = wr >> 4;
  const int bcol = wc >> 4;

  const s16x8* xh8 = (const s16x8*)xhi;
  const s16x8* th8 = (const s16x8*)thi;

  float tv[KTOP]; int tix[KTOP];
#pragma unroll
  for (int s = 0; s < KTOP; ++s) { tv[s] = FLT_MAX; tix[s] = 0x7FFFFFFF; }

#pragma unroll 1
  for (int tt = tstart; tt < tend; ++tt) {
    const int bblk = chunk * NTPC + tt;
    if (bblk >= TBLKS) continue;   // fully past NT: partials stay FLT_MAX
    const int jbase = bblk * TTILE;
    f32x4 acc[4][4];
#pragma unroll
    for (int i = 0; i < 4; ++i)
#pragma unroll
      for (int j = 0; j < 4; ++j) acc[i][j] = (f32x4){0.f, 0.f, 0.f, 0.f};

    // element offsets (s16x8 units); kbi stride = 512 units (8192 B)
    u32 offA = (u32)(qblk * 16) * 512u + (u32)(arow * 64 + l);
    u32 offB = (u32)(bblk * 16) * 512u + (u32)(bcol * 64 + l);
    s16x8 ah[4], bh[4];
#pragma unroll 1
    for (int kbi = 0; kbi < 16; ++kbi) {
#pragma unroll
      for (int i = 0; i < 4; ++i) {
        ah[i] = xh8[offA + i * 64];
        bh[i] = th8[offB + i * 64];
      }
      offA += 512; offB += 512;
      __builtin_amdgcn_s_setprio(1);
#pragma unroll
      for (int j = 0; j < 4; ++j)
#pragma unroll
        for (int i = 0; i < 4; ++i)
          acc[i][j] = __builtin_amdgcn_mfma_f32_16x16x32_bf16(ah[i], bh[j], acc[i][j], 0, 0, 0);
      __builtin_amdgcn_s_setprio(0);
    }

    // epilogue: transpose C through wave-private LDS scratch; per-lane top-5
    float* scr = scr_all + w * 1280;  // 64 rows x 20 (pad)
#pragma unroll
    for (int jj = 0; jj < 4; ++jj) {
      int colg = jbase + wc + jj * 16 + (l & 15);
      int cc = colg < NT ? colg : NT - 1;
      float t2v = t2g[cc];
      bool valid = colg < NT;
#pragma unroll
      for (int i = 0; i < 4; ++i)
#pragma unroll
        for (int r = 0; r < 4; ++r) {
          float sc = valid ? fmaf(-2.f, acc[i][jj][r], t2v) : FLT_MAX;
          int rowl = i * 16 + ((l >> 4) << 2) + r;
          scr[rowl * 20 + (l & 15)] = sc;
        }
      int cbg = jbase + wc + jj * 16;
#pragma unroll
      for (int c4 = 0; c4 < 4; ++c4) {
        f32x4 rv = *(const f32x4*)(scr + l * 20 + c4 * 4);
#pragma unroll
        for (int c = 0; c < 4; ++c) ins5(tv, tix, rv[c], cbg + c4 * 4 + c);
      }
    }
  }

  // cross-wave merge: waves (0,1) share rows 0-63, (2,3) rows 64-127
  __syncthreads();
  float* ms = scr_all;
  int* msi = (int*)scr_all + 640;
  if (w & 1) {
    int rid = wr + l;
#pragma unroll
    for (int s = 0; s < KTOP; ++s) { ms[rid * 5 + s] = tv[s]; msi[rid * 5 + s] = tix[s]; }
  }
  __syncthreads();
  if (!(w & 1)) {
    int rid = wr + l;
    float ov[KTOP]; int oi[KTOP];
#pragma unroll
    for (int s = 0; s < KTOP; ++s) { ov[s] = ms[rid * 5 + s]; oi[s] = msi[rid * 5 + s]; }
    merge5(tv, tix, ov, oi);
    int q = q0 + rid;
    // u16 local index: block covers <=3 tiles = 384 t's from blockBase.
    // FLT_MAX sentinel entries may carry garbage offsets - never selected.
    const int blockBase = (chunk * NTPC + tstart) * TTILE;
    size_t base = ((size_t)q * (NCH * NSUB) + (chunk * NSUB + tsub)) * KTOP;
#pragma unroll
    for (int s = 0; s < KTOP; ++s) {
      pvals[base + s] = tv[s];
      pidx16[base + s] = (u16)(tix[s] - blockBase);
    }
  }
}

// ---------------- merge16: 1920 approx partials -> top-16 indices/query -----
// One wave per query. 16 rounds of global argmin via butterfly reduce; the
// owning lane masks the winner. All register arrays statically indexed.
__global__ __launch_bounds__(256) void knn_merge16(
    const float* __restrict__ pvals, const u16* __restrict__ pidx16,
    int* __restrict__ idx16g) {
  const int M = NCH * NSUB * KTOP;  // 1920 = 64 lanes x 30
  int q = (blockIdx.x * 256 + threadIdx.x) >> 6;
  int l = threadIdx.x & 63;
  if (q >= NQ) return;
  float v[30]; int ix[30];
  size_t base = (size_t)q * M;
#pragma unroll
  for (int j = 0; j < 30; ++j) {
    int m = j * 64 + l;
    int slot = m / KTOP;                    // candidate slot = chunk*NSUB+tsub
    int ch = slot / NSUB, ts = slot % NSUB;
    int gb = (ch * NTPC + tsub_start(ts)) * TTILE;
    v[j] = pvals[base + m];
    ix[j] = gb + (int)pidx16[base + m];
  }
  int mywin = 0x7FFFFFFF;
#pragma unroll 1
  for (int r = 0; r < NCAND; ++r) {
    float bv = FLT_MAX; int bi = 0x7FFFFFFF;
#pragma unroll
    for (int j = 0; j < 30; ++j)
      if (lt_pair(v[j], ix[j], bv, bi)) { bv = v[j]; bi = ix[j]; }
#pragma unroll
    for (int d = 1; d < 64; d <<= 1) {
      float ov = __shfl_xor(bv, d, 64);
      int oi = __shfl_xor(bi, d, 64);
      if (lt_pair(ov, oi, bv, bi)) { bv = ov; bi = oi; }
    }
    if (l == r) mywin = bi;     // all lanes agree on bi; lane r records it
#pragma unroll
    for (int j = 0; j < 30; ++j)
      if (ix[j] == bi) v[j] = FLT_MAX;      // global idx unique -> safe mask
  }
  if (l < NCAND) idx16g[q * NCAND + l] = mywin;
}

// ---------------- rerank: exact fp32 d2 for 16 cands/query -> final top-5 ---
// One wave per query (4/block). 4 lanes per candidate, 128 dims each; dot,
// |t|^2, |x|^2 computed from the ORIGINAL fp32 arrays in one pass.
__global__ __launch_bounds__(256) void knn_rerank(
    const float* __restrict__ x, const float* __restrict__ T,
    const int* __restrict__ idx16g, const int* __restrict__ labels,
    float* __restrict__ out) {
  __shared__ float sd2[4 * NCAND];
  __shared__ int sti[4 * NCAND];
  const int w = threadIdx.x >> 6, l = threadIdx.x & 63;
  const int q = blockIdx.x * 4 + w;
  const int cand = l >> 2, sub = l & 3;
  const int ti = idx16g[q * NCAND + cand];
  const f32x4* tp = (const f32x4*)(T + (size_t)ti * DIM + sub * 128);
  const f32x4* xp = (const f32x4*)(x + (size_t)q * DIM + sub * 128);
  float dot = 0.f, tt = 0.f, xx = 0.f;
#pragma unroll
  for (int i = 0; i < 32; ++i) {
    f32x4 a = xp[i], b = tp[i];
#pragma unroll
    for (int c = 0; c < 4; ++c) {
      dot = fmaf(a[c], b[c], dot);
      tt  = fmaf(b[c], b[c], tt);
      xx  = fmaf(a[c], a[c], xx);
    }
  }
#pragma unroll
  for (int d = 1; d < 4; d <<= 1) {
    dot += __shfl_xor(dot, d, 64);
    tt  += __shfl_xor(tt, d, 64);
    xx  += __shfl_xor(xx, d, 64);
  }
  if (sub == 0) { sd2[w * NCAND + cand] = xx + tt - 2.f * dot; sti[w * NCAND + cand] = ti; }
  __syncthreads();
  if (l == 0) {
    float tv[KTOP]; int tix[KTOP];
#pragma unroll
    for (int s = 0; s < KTOP; ++s) { tv[s] = FLT_MAX; tix[s] = 0x7FFFFFFF; }
#pragma unroll
    for (int c = 0; c < NCAND; ++c) ins5(tv, tix, sd2[w * NCAND + c], sti[w * NCAND + c]);
#pragma unroll
    for (int s = 0; s < KTOP; ++s) {
      float d2 = tv[s] > 0.f ? tv[s] : 0.f;
      out[(size_t)q * KTOP + s] = sqrtf(d2);                          // topk_dists [Q,K]
      out[(size_t)NQ * KTOP + (size_t)q * KTOP + s] = (float)tix[s];  // topk_inds [Q,K]
      out[(size_t)2 * NQ * KTOP + (size_t)s * NQ + q] =
          (float)labels[tix[s]];                                       // pred [K,Q]
    }
  }
}

extern "C" void kernel_launch(void* const* d_in, const int* in_sizes, int n_in,
                              void* d_out, int out_size, void* d_ws, size_t ws_size,
                              hipStream_t stream) {
  const float* x = (const float*)d_in[0];
  const float* T = (const float*)d_in[1];
  const int* labels = (const int*)d_in[2];
  float* out = (float*)d_out;
  char* ws = (char*)d_ws;

  // ws layout (bytes), total ~128.7 MB (was ~233 MB; mid arrays dropped)
  float* t2    = (float*)(ws + 0);              // 400,000
  float* x2    = (float*)(ws + 401408);         // 8,192
  short* xhi   = (short*)(ws + 409600);         // 2,097,152
  short* thi   = (short*)(ws + 2506752);        // 102,498,304 (end 105,005,056)
  float* pvals = (float*)(ws + 105005056);      // 15,728,640
  u16*   pidx16 = (u16*)(ws + 120733696);       // 7,864,320
  int*   idx16g = (int*)(ws + 128598016);       // 131,072 (end 128,729,088)

  hipMemsetAsync(ws, 0, 409600, stream);        // zero t2/x2 for atomic norms

  convert_kernel<<<CV_TBLKS + CV_XBLKS, 256, 0, stream>>>(
      x, T, xhi, thi, t2, x2);

  knn_mfma<<<QBLKS * NSUB * NCH, 256, 0, stream>>>(
      xhi, thi, t2, pvals, pidx16);

  knn_merge16<<<(NQ * 64 + 255) / 256, 256, 0, stream>>>(pvals, pidx16, idx16g);

  knn_rerank<<<NQ / 4, 256, 0, stream>>>(x, T, idx16g, labels, out);
}